// Round 19
// baseline (74.591 us; speedup 1.0000x reference)
//
#include <hip/hip_runtime.h>

#define SUPPORT 512
#define TARGET  65024
#define NCLS    64
#define NQUAD   (TARGET / 4)       // 16256 row-quads for direct part
#define GS_ROWS 64
#define GS_BLK  (TARGET / GS_ROWS) // 1016 stream blocks
#define PH_ROWS 256
#define PH_BLK  (TARGET / PH_ROWS) // 254 pos_hist blocks (8 thr/row, 256 rows/block)
#define DR_BLK  1024               // direct blocks (in stream dispatch)

struct Accum {
    float hist_fr[80];          // Σfrac per bin (pos elements)
    float hist_cnt[80];         // count per bin (pos elements)
    float sum_all[8];
    float nll_sum[8];
    float spos;                 // closed-form sum_pos (stream block 0)
    float pos_num;              // total positive count (stream block 0)
};

__device__ __forceinline__ void lds_fadd(float* p, float v) {
    __hip_atomic_fetch_add(p, v, __ATOMIC_RELAXED, __HIP_MEMORY_SCOPE_WORKGROUP);
}

// ---------------------------------------------------------------- poshist (pure)
// Each block builds its own CSR, then gathers 256 rows' positive columns with a
// two-phase scheme: issue 16 independent predicated loads (8 rows x 2 slots,
// covers cnt<=16 which is ~99.8% of rows), then process; rare cleanup for
// cnt>16. 16-deep MLP per thread.
__global__ __launch_bounds__(256) void poshist_kernel(const float* __restrict__ ip,
                                                      const int* __restrict__ labels,
                                                      Accum* __restrict__ ws) {
    const int tid = threadIdx.x;
    __shared__ float hfr[76][8];
    __shared__ float hcnt[76][8];
    __shared__ int   colL[SUPPORT];
    __shared__ int   offL[NCLS + 1];
    __shared__ int   cntL[NCLS], curL[NCLS];
    for (int i = tid; i < 76 * 8; i += 256) {
        (&hfr[0][0])[i] = 0.0f;
        (&hcnt[0][0])[i] = 0.0f;
    }
    if (tid < NCLS) cntL[tid] = 0;
    __syncthreads();
    const int j0 = tid, j1 = tid + 256;
    const int l0 = labels[j0], l1 = labels[j1];
    atomicAdd(&cntL[l0], 1);
    atomicAdd(&cntL[l1], 1);
    __syncthreads();
    if (tid == 0) {
        int o = 0;
        for (int i = 0; i < NCLS; ++i) { offL[i] = o; curL[i] = o; o += cntL[i]; }
        offL[NCLS] = o;
    }
    __syncthreads();
    colL[atomicAdd(&curL[l0], 1)] = j0;
    colL[atomicAdd(&curL[l1], 1)] = j1;
    __syncthreads();

    const int sl = tid & 7;
    const int r0 = blockIdx.x * PH_ROWS + (tid >> 3);   // rows r0 + 32*{0..7}

    int   base_[8], cnt_[8];
    float v0_[8], v1_[8];
    // phase A: compute bases, issue up to 16 independent predicated loads
    #pragma unroll
    for (int rr = 0; rr < 8; ++rr) {
        const int r = r0 + rr * 32;
        const int c = labels[SUPPORT + r];
        base_[rr] = offL[c];
        cnt_[rr]  = offL[c + 1] - base_[rr];
        const float* rptr = ip + (size_t)r * SUPPORT;
        v0_[rr] = (sl     < cnt_[rr]) ? rptr[colL[base_[rr] + sl]]     : 0.0f;
        v1_[rr] = (sl + 8 < cnt_[rr]) ? rptr[colL[base_[rr] + sl + 8]] : 0.0f;
    }
    // phase B: process
    #pragma unroll
    for (int rr = 0; rr < 8; ++rr) {
        if (sl < cnt_[rr]) {
            const float u  = v0_[rr] * 75.0f;
            const float fl = floorf(u);
            const int idx  = (int)fl;            // 0..74 guaranteed (s in [0,1))
            lds_fadd(&hfr[idx][sl],  u - fl);
            lds_fadd(&hcnt[idx][sl], 1.0f);
        }
        if (sl + 8 < cnt_[rr]) {
            const float u  = v1_[rr] * 75.0f;
            const float fl = floorf(u);
            const int idx  = (int)fl;
            lds_fadd(&hfr[idx][sl],  u - fl);
            lds_fadd(&hcnt[idx][sl], 1.0f);
        }
    }
    // phase C: rare cleanup for cnt > 16
    #pragma unroll
    for (int rr = 0; rr < 8; ++rr) {
        if (cnt_[rr] > 16) {
            const float* rptr = ip + (size_t)(r0 + rr * 32) * SUPPORT;
            for (int j = sl + 16; j < cnt_[rr]; j += 8) {
                const float s  = rptr[colL[base_[rr] + j]];
                const float u  = s * 75.0f;
                const float fl = floorf(u);
                const int idx  = (int)fl;
                lds_fadd(&hfr[idx][sl],  u - fl);
                lds_fadd(&hcnt[idx][sl], 1.0f);
            }
        }
    }
    __syncthreads();
    if (tid < 76) {
        float a = 0.0f, b = 0.0f;
        #pragma unroll
        for (int r = 0; r < 8; ++r) { a += hfr[tid][r]; b += hcnt[tid][r]; }
        if (a != 0.0f) unsafeAtomicAdd(&ws->hist_fr[tid], a);
        if (b != 0.0f) unsafeAtomicAdd(&ws->hist_cnt[tid], b);
    }
}

// ---------------------------------------------------------------- stream + direct (one dispatch)
// Stream blocks: cdf prologue (read 76-bin hist; float-only one-lane scan ->
// fused Ta/Tb table, 32-way replicated; block 0 adds double spos/pos_num), then
// 64 contiguous rows via named-register 2x8-deep pipeline.
// Direct blocks: 4 rows/wave, 16-lane group per row.
__global__ __launch_bounds__(256, 4) void stream_kernel(const float* __restrict__ ip,
                                                        const float* __restrict__ logits,
                                                        const int* __restrict__ labels,
                                                        Accum* __restrict__ ws) {
    __shared__ float2 tab[76 * 32];   // 32-way replicated fused table (19.5 KB)
    __shared__ float Sfr[80], Cnt[80];
    __shared__ float Atab[80], Btab[80];
    __shared__ float red[4];
    const int tid = threadIdx.x;

    if (blockIdx.x >= GS_BLK) {
        // ---- direct loss
        const int bid  = blockIdx.x - GS_BLK;
        const int wid  = tid >> 6;
        const int lane = tid & 63;
        const int sub  = lane >> 4;
        const int grpb = lane & ~15;

        float lsum = 0.0f;
        for (int q = bid * 4 + wid; q < NQUAD; q += DR_BLK * 4) {
            const float4 x = reinterpret_cast<const float4*>(logits)[q * 64 + lane];
            const int lab  = labels[SUPPORT + q * 4 + sub];
            float m = fmaxf(fmaxf(x.x, x.y), fmaxf(x.z, x.w));
            #pragma unroll
            for (int off = 1; off < 16; off <<= 1) m = fmaxf(m, __shfl_xor(m, off));
            float e = __expf(x.x - m) + __expf(x.y - m) + __expf(x.z - m) + __expf(x.w - m);
            #pragma unroll
            for (int off = 1; off < 16; off <<= 1) e += __shfl_xor(e, off);
            const int l3 = lab & 3;
            const float sel = l3 == 0 ? x.x : l3 == 1 ? x.y : l3 == 2 ? x.z : x.w;
            const float xl = __shfl(sel, grpb + (lab >> 2));
            if ((lane & 15) == 0) lsum += m + __logf(e) - xl;
        }
        #pragma unroll
        for (int off = 1; off < 64; off <<= 1) lsum += __shfl_xor(lsum, off);
        if (lane == 0) red[wid] = lsum;
        __syncthreads();
        if (tid == 0)
            unsafeAtomicAdd(&ws->nll_sum[bid & 7], red[0] + red[1] + red[2] + red[3]);
        return;
    }

    // ---- stream path: cdf prologue
    if (tid < 76) { Sfr[tid] = ws->hist_fr[tid]; Cnt[tid] = ws->hist_cnt[tid]; }
    if (tid >= 76 && tid < 80) { Sfr[tid] = 0.0f; Cnt[tid] = 0.0f; }
    __syncthreads();
    if (tid == 0) {
        if (blockIdx.x == 0) {
            float prevS = 0.0f, prevN = 0.0f, cacc = 0.0f;
            double sp = 0.0, pn = 0.0;
            for (int i = 0; i <= 76; ++i) {
                const float Si = (i < 76) ? Sfr[i] : 0.0f;
                const float Ni = (i < 76) ? Cnt[i] : 0.0f;
                const float Hi = Si + prevN - prevS;     // pos soft-hist H[i]
                cacc += Hi;                              // C[i]
                if (i >= 1) {
                    const int k = i - 1;
                    Atab[k] = cacc + (float)k * Hi;      // C[k+1] + k*H[k+1]
                    Btab[k] = Hi;                        // H[k+1]
                    sp += (double)prevN * cacc - (double)prevS * Hi;
                }
                pn += (double)Ni;
                prevS = Si; prevN = Ni;
            }
            ws->spos = (float)sp; ws->pos_num = (float)pn;
        } else {
            float prevS = 0.0f, prevN = 0.0f, cacc = 0.0f;
            for (int i = 0; i <= 76; ++i) {
                const float Si = (i < 76) ? Sfr[i] : 0.0f;
                const float Ni = (i < 76) ? Cnt[i] : 0.0f;
                const float Hi = Si + prevN - prevS;
                cacc += Hi;
                if (i >= 1) {
                    const int k = i - 1;
                    Atab[k] = cacc + (float)k * Hi;
                    Btab[k] = Hi;
                }
                prevS = Si; prevN = Ni;
            }
        }
    }
    __syncthreads();
    const int c32 = tid & 31;
    for (int i = tid; i < 76 * 32; i += 256)
        tab[i] = make_float2(Atab[i >> 5], Btab[i >> 5]);
    __syncthreads();

    const float4* base = reinterpret_cast<const float4*>(ip)
                       + (size_t)blockIdx.x * (GS_ROWS * 128) + tid;

    float sa0 = 0.0f, sb0 = 0.0f, sa1 = 0.0f, sb1 = 0.0f;
    float4 qa0, qa1, qa2, qa3, qa4, qa5, qa6, qa7;
    float4 qb0, qb1, qb2, qb3, qb4, qb5, qb6, qb7;

#define LDA(T) { qa0 = base[((T)+0)*256]; qa1 = base[((T)+1)*256]; \
                 qa2 = base[((T)+2)*256]; qa3 = base[((T)+3)*256]; \
                 qa4 = base[((T)+4)*256]; qa5 = base[((T)+5)*256]; \
                 qa6 = base[((T)+6)*256]; qa7 = base[((T)+7)*256]; }
#define LDB(T) { qb0 = base[((T)+0)*256]; qb1 = base[((T)+1)*256]; \
                 qb2 = base[((T)+2)*256]; qb3 = base[((T)+3)*256]; \
                 qb4 = base[((T)+4)*256]; qb5 = base[((T)+5)*256]; \
                 qb6 = base[((T)+6)*256]; qb7 = base[((T)+7)*256]; }
#define PE(S, SA, SB) { const float u = (S) * 75.0f; const int idx = (int)u;   \
                        const float2 ab = tab[(idx << 5) + c32];               \
                        SA += ab.x; SB = fmaf(u, ab.y, SB); }
#define P1(Q) { PE(Q.x, sa0, sb0) PE(Q.y, sa1, sb1) PE(Q.z, sa0, sb0) PE(Q.w, sa1, sb1) }
#define PA()  { P1(qa0) P1(qa1) P1(qa2) P1(qa3) P1(qa4) P1(qa5) P1(qa6) P1(qa7) }
#define PB()  { P1(qb0) P1(qb1) P1(qb2) P1(qb3) P1(qb4) P1(qb5) P1(qb6) P1(qb7) }

    LDA(0);
    LDB(8);
    PA();  LDA(16);
    PB();  LDB(24);
    PA();
    PB();

#undef LDA
#undef LDB
#undef PE
#undef P1
#undef PA
#undef PB

    float s_all = (sa0 + sa1) - (sb0 + sb1);
    #pragma unroll
    for (int off = 1; off < 64; off <<= 1) s_all += __shfl_xor(s_all, off);
    if ((tid & 63) == 0) red[tid >> 6] = s_all;
    __syncthreads();
    if (tid == 0)
        unsafeAtomicAdd(&ws->sum_all[blockIdx.x & 7], red[0] + red[1] + red[2] + red[3]);
}

// ---------------------------------------------------------------- finalize
__global__ void final_kernel(const Accum* __restrict__ ws, float* __restrict__ out) {
    if (threadIdx.x == 0 && blockIdx.x == 0) {
        double S = 0.0, nll = 0.0;
        for (int i = 0; i < 8; ++i) {
            S   += (double)ws->sum_all[i];
            nll += (double)ws->nll_sum[i];
        }
        const double pos = (double)ws->pos_num;
        const double tot = (double)TARGET * (double)SUPPORT;
        out[0] = (float)((S - (double)ws->spos) / (pos * (tot - pos)));
        out[1] = (float)(nll / (double)TARGET);
    }
}

// ---------------------------------------------------------------- launch
extern "C" void kernel_launch(void* const* d_in, const int* in_sizes, int n_in,
                              void* d_out, int out_size, void* d_ws, size_t ws_size,
                              hipStream_t stream) {
    const float* logits = (const float*)d_in[0];   // (65024, 64) f32
    const float* ip     = (const float*)d_in[1];   // (65024, 512) f32
    const int*   labels = (const int*)d_in[2];     // (65536,) int
    float* out = (float*)d_out;
    Accum* ws  = (Accum*)d_ws;

    hipMemsetAsync(ws, 0, sizeof(Accum), stream);
    poshist_kernel<<<PH_BLK, 256, 0, stream>>>(ip, labels, ws);
    stream_kernel<<<GS_BLK + DR_BLK, 256, 0, stream>>>(ip, logits, labels, ws);
    final_kernel<<<1, 64, 0, stream>>>(ws, out);
}

// Round 20
// 68.708 us; speedup vs baseline: 1.0856x; 1.0856x over previous
//
#include <hip/hip_runtime.h>

#define SUPPORT 512
#define TARGET  65024
#define NCLS    64
#define NQUAD   (TARGET / 4)       // 16256 row-quads for direct part
#define GS_ROWS 64
#define GS_BLK  (TARGET / GS_ROWS) // 1016 stream blocks
#define PH_ROWS 128
#define PH_BLK  (TARGET / PH_ROWS) // 508 pos_hist blocks (8 thr/row, 128 rows/block)
#define DR_BLK  1024               // direct blocks (in poshist dispatch)

struct Accum {
    float hist_fr_sp[8][80];    // spread Σfrac per bin (pos elements)
    float hist_cnt_sp[8][80];   // spread counts per bin (pos elements)
    float sum_all[8];
    float nll_sum[8];
    float spos;                 // closed-form sum_pos (stream block 0)
    float pos_num;              // total positive count (stream block 0)
};

__device__ __forceinline__ void lds_fadd(float* p, float v) {
    __hip_atomic_fetch_add(p, v, __ATOMIC_RELAXED, __HIP_MEMORY_SCOPE_WORKGROUP);
}

// ---------------------------------------------------------------- poshist + direct (one dispatch)
// poshist blocks build their own CSR of support columns per class, then
// process 128 rows (4 independent scattered loads per thread).
__global__ __launch_bounds__(256) void phdir_kernel(const float* __restrict__ ip,
                                                    const float* __restrict__ logits,
                                                    const int* __restrict__ labels,
                                                    Accum* __restrict__ ws) {
    const int tid = threadIdx.x;
    if (blockIdx.x < PH_BLK) {
        // ---- pos (Sfr, Cnt) histogram: 8 threads per target row, 128 rows/block
        __shared__ float hfr[76][8];
        __shared__ float hcnt[76][8];
        __shared__ int   colL[SUPPORT];
        __shared__ int   offL[NCLS + 1];
        __shared__ int   cntL[NCLS], curL[NCLS];
        for (int i = tid; i < 76 * 8; i += 256) {
            (&hfr[0][0])[i] = 0.0f;
            (&hcnt[0][0])[i] = 0.0f;
        }
        if (tid < NCLS) cntL[tid] = 0;
        __syncthreads();
        const int j0 = tid, j1 = tid + 256;
        const int l0 = labels[j0], l1 = labels[j1];
        atomicAdd(&cntL[l0], 1);
        atomicAdd(&cntL[l1], 1);
        __syncthreads();
        if (tid == 0) {
            int o = 0;
            for (int i = 0; i < NCLS; ++i) { offL[i] = o; curL[i] = o; o += cntL[i]; }
            offL[NCLS] = o;
        }
        __syncthreads();
        colL[atomicAdd(&curL[l0], 1)] = j0;
        colL[atomicAdd(&curL[l1], 1)] = j1;
        __syncthreads();

        const int sl = tid & 7;
        const int r0 = blockIdx.x * PH_ROWS + (tid >> 3);   // rows r0 + {0,32,64,96}
        #pragma unroll
        for (int rr = 0; rr < 4; ++rr) {
            const int r    = r0 + rr * 32;
            const int c    = labels[SUPPORT + r];
            const int base = offL[c];
            const int cnt  = offL[c + 1] - base;
            const float* rptr = ip + (size_t)r * SUPPORT;
            for (int j = sl; j < cnt; j += 8) {
                const float s  = rptr[colL[base + j]];
                const float u  = s * 75.0f;
                const float fl = floorf(u);
                const int idx  = (int)fl;            // 0..74 guaranteed (s in [0,1))
                lds_fadd(&hfr[idx][sl],  u - fl);
                lds_fadd(&hcnt[idx][sl], 1.0f);
            }
        }
        __syncthreads();
        if (tid < 76) {
            float a = 0.0f, b = 0.0f;
            #pragma unroll
            for (int r = 0; r < 8; ++r) { a += hfr[tid][r]; b += hcnt[tid][r]; }
            if (a != 0.0f) unsafeAtomicAdd(&ws->hist_fr_sp[blockIdx.x & 7][tid], a);
            if (b != 0.0f) unsafeAtomicAdd(&ws->hist_cnt_sp[blockIdx.x & 7][tid], b);
        }
    } else {
        // ---- direct loss: 4 rows per wave, 16-lane group per row
        __shared__ float red[4];
        const int bid  = blockIdx.x - PH_BLK;
        const int wid  = tid >> 6;
        const int lane = tid & 63;
        const int sub  = lane >> 4;
        const int grpb = lane & ~15;

        float lsum = 0.0f;
        for (int q = bid * 4 + wid; q < NQUAD; q += DR_BLK * 4) {
            const float4 x = reinterpret_cast<const float4*>(logits)[q * 64 + lane];
            const int lab  = labels[SUPPORT + q * 4 + sub];
            float m = fmaxf(fmaxf(x.x, x.y), fmaxf(x.z, x.w));
            #pragma unroll
            for (int off = 1; off < 16; off <<= 1) m = fmaxf(m, __shfl_xor(m, off));
            float e = __expf(x.x - m) + __expf(x.y - m) + __expf(x.z - m) + __expf(x.w - m);
            #pragma unroll
            for (int off = 1; off < 16; off <<= 1) e += __shfl_xor(e, off);
            const int l3 = lab & 3;
            const float sel = l3 == 0 ? x.x : l3 == 1 ? x.y : l3 == 2 ? x.z : x.w;
            const float xl = __shfl(sel, grpb + (lab >> 2));
            if ((lane & 15) == 0) lsum += m + __logf(e) - xl;
        }
        #pragma unroll
        for (int off = 1; off < 64; off <<= 1) lsum += __shfl_xor(lsum, off);
        if (lane == 0) red[wid] = lsum;
        __syncthreads();
        if (tid == 0)
            unsafeAtomicAdd(&ws->nll_sum[bid & 7], red[0] + red[1] + red[2] + red[3]);
    }
}

// ---------------------------------------------------------------- stream (cdf prologue folded in)
// Prologue: reduce spread hists; float-only one-lane scan -> fused Ta/Tb table,
// 32-way replicated float2 (2-way bank alias only -> free). Block 0 additionally
// accumulates spos/pos_num in double.
// Main: 64 contiguous rows, named-register 2x8-deep load pipeline; per element:
// u=s*75; idx=(int)u; ds_read_b64; add + fma.
__global__ __launch_bounds__(256, 4) void stream_kernel(const float* __restrict__ ip,
                                                        Accum* __restrict__ ws) {
    __shared__ float2 tab[76 * 32];   // 32-way replicated fused table (19.5 KB)
    __shared__ float Sfr[80], Cnt[80];
    __shared__ float Atab[80], Btab[80];
    __shared__ float red[4];
    const int tid = threadIdx.x;

    if (tid < 76) {
        float a = 0.0f, b = 0.0f;
        #pragma unroll
        for (int r = 0; r < 8; ++r) { a += ws->hist_fr_sp[r][tid]; b += ws->hist_cnt_sp[r][tid]; }
        Sfr[tid] = a; Cnt[tid] = b;
    }
    if (tid >= 76 && tid < 80) { Sfr[tid] = 0.0f; Cnt[tid] = 0.0f; }
    __syncthreads();
    if (tid == 0) {
        if (blockIdx.x == 0) {
            float prevS = 0.0f, prevN = 0.0f, cacc = 0.0f;
            double sp = 0.0, pn = 0.0;
            for (int i = 0; i <= 76; ++i) {
                const float Si = (i < 76) ? Sfr[i] : 0.0f;
                const float Ni = (i < 76) ? Cnt[i] : 0.0f;
                const float Hi = Si + prevN - prevS;     // pos soft-hist H[i]
                cacc += Hi;                              // C[i]
                if (i >= 1) {
                    const int k = i - 1;
                    Atab[k] = cacc + (float)k * Hi;      // C[k+1] + k*H[k+1]
                    Btab[k] = Hi;                        // H[k+1]
                    sp += (double)prevN * cacc - (double)prevS * Hi;
                }
                pn += (double)Ni;
                prevS = Si; prevN = Ni;
            }
            ws->spos = (float)sp; ws->pos_num = (float)pn;
        } else {
            float prevS = 0.0f, prevN = 0.0f, cacc = 0.0f;
            for (int i = 0; i <= 76; ++i) {
                const float Si = (i < 76) ? Sfr[i] : 0.0f;
                const float Ni = (i < 76) ? Cnt[i] : 0.0f;
                const float Hi = Si + prevN - prevS;
                cacc += Hi;
                if (i >= 1) {
                    const int k = i - 1;
                    Atab[k] = cacc + (float)k * Hi;
                    Btab[k] = Hi;
                }
                prevS = Si; prevN = Ni;
            }
        }
    }
    __syncthreads();
    const int c32 = tid & 31;
    for (int i = tid; i < 76 * 32; i += 256)
        tab[i] = make_float2(Atab[i >> 5], Btab[i >> 5]);
    __syncthreads();

    const float4* base = reinterpret_cast<const float4*>(ip)
                       + (size_t)blockIdx.x * (GS_ROWS * 128) + tid;

    float sa0 = 0.0f, sb0 = 0.0f, sa1 = 0.0f, sb1 = 0.0f;
    float4 qa0, qa1, qa2, qa3, qa4, qa5, qa6, qa7;
    float4 qb0, qb1, qb2, qb3, qb4, qb5, qb6, qb7;

#define LDA(T) { qa0 = base[((T)+0)*256]; qa1 = base[((T)+1)*256]; \
                 qa2 = base[((T)+2)*256]; qa3 = base[((T)+3)*256]; \
                 qa4 = base[((T)+4)*256]; qa5 = base[((T)+5)*256]; \
                 qa6 = base[((T)+6)*256]; qa7 = base[((T)+7)*256]; }
#define LDB(T) { qb0 = base[((T)+0)*256]; qb1 = base[((T)+1)*256]; \
                 qb2 = base[((T)+2)*256]; qb3 = base[((T)+3)*256]; \
                 qb4 = base[((T)+4)*256]; qb5 = base[((T)+5)*256]; \
                 qb6 = base[((T)+6)*256]; qb7 = base[((T)+7)*256]; }
#define PE(S, SA, SB) { const float u = (S) * 75.0f; const int idx = (int)u;   \
                        const float2 ab = tab[(idx << 5) + c32];               \
                        SA += ab.x; SB = fmaf(u, ab.y, SB); }
#define P1(Q) { PE(Q.x, sa0, sb0) PE(Q.y, sa1, sb1) PE(Q.z, sa0, sb0) PE(Q.w, sa1, sb1) }
#define PA()  { P1(qa0) P1(qa1) P1(qa2) P1(qa3) P1(qa4) P1(qa5) P1(qa6) P1(qa7) }
#define PB()  { P1(qb0) P1(qb1) P1(qb2) P1(qb3) P1(qb4) P1(qb5) P1(qb6) P1(qb7) }

    LDA(0);
    LDB(8);
    PA();  LDA(16);
    PB();  LDB(24);
    PA();
    PB();

#undef LDA
#undef LDB
#undef PE
#undef P1
#undef PA
#undef PB

    float s_all = (sa0 + sa1) - (sb0 + sb1);
    #pragma unroll
    for (int off = 1; off < 64; off <<= 1) s_all += __shfl_xor(s_all, off);
    if ((tid & 63) == 0) red[tid >> 6] = s_all;
    __syncthreads();
    if (tid == 0)
        unsafeAtomicAdd(&ws->sum_all[blockIdx.x & 7], red[0] + red[1] + red[2] + red[3]);
}

// ---------------------------------------------------------------- finalize
__global__ void final_kernel(const Accum* __restrict__ ws, float* __restrict__ out) {
    if (threadIdx.x == 0 && blockIdx.x == 0) {
        double S = 0.0, nll = 0.0;
        for (int i = 0; i < 8; ++i) {
            S   += (double)ws->sum_all[i];
            nll += (double)ws->nll_sum[i];
        }
        const double pos = (double)ws->pos_num;
        const double tot = (double)TARGET * (double)SUPPORT;
        out[0] = (float)((S - (double)ws->spos) / (pos * (tot - pos)));
        out[1] = (float)(nll / (double)TARGET);
    }
}

// ---------------------------------------------------------------- launch
extern "C" void kernel_launch(void* const* d_in, const int* in_sizes, int n_in,
                              void* d_out, int out_size, void* d_ws, size_t ws_size,
                              hipStream_t stream) {
    const float* logits = (const float*)d_in[0];   // (65024, 64) f32
    const float* ip     = (const float*)d_in[1];   // (65024, 512) f32
    const int*   labels = (const int*)d_in[2];     // (65536,) int
    float* out = (float*)d_out;
    Accum* ws  = (Accum*)d_ws;

    hipMemsetAsync(ws, 0, sizeof(Accum), stream);
    phdir_kernel<<<PH_BLK + DR_BLK, 256, 0, stream>>>(ip, logits, labels, ws);
    stream_kernel<<<GS_BLK, 256, 0, stream>>>(ip, ws);
    final_kernel<<<1, 64, 0, stream>>>(ws, out);
}

// Round 22
// 67.033 us; speedup vs baseline: 1.1127x; 1.0250x over previous
//
#include <hip/hip_runtime.h>

#define SUPPORT 512
#define TARGET  65024
#define NCLS    64
#define NQUAD   (TARGET / 4)       // 16256 row-quads for direct part
#define GS_ROWS 64
#define GS_BLK  (TARGET / GS_ROWS) // 1016 stream blocks
#define PH_ROWS 128
#define PH_BLK  (TARGET / PH_ROWS) // 508 pos_hist blocks (8 thr/row, 128 rows/block)
#define DR_BLK  1024               // direct blocks (in poshist dispatch)

typedef float f4 __attribute__((ext_vector_type(4)));   // clang vector: legal for nontemporal builtins

struct Accum {
    float hist_fr_sp[8][80];    // spread Σfrac per bin (pos elements)
    float hist_cnt_sp[8][80];   // spread counts per bin (pos elements)
    float sum_all[8];
    float nll_sum[8];
    float spos;                 // closed-form sum_pos (stream block 0)
    float pos_num;              // total positive count (stream block 0)
};

__device__ __forceinline__ void lds_fadd(float* p, float v) {
    __hip_atomic_fetch_add(p, v, __ATOMIC_RELAXED, __HIP_MEMORY_SCOPE_WORKGROUP);
}

// ---------------------------------------------------------------- poshist + direct (one dispatch)
__global__ __launch_bounds__(256) void phdir_kernel(const float* __restrict__ ip,
                                                    const float* __restrict__ logits,
                                                    const int* __restrict__ labels,
                                                    Accum* __restrict__ ws) {
    const int tid = threadIdx.x;
    if (blockIdx.x < PH_BLK) {
        // ---- pos (Sfr, Cnt) histogram: 8 threads per target row, 128 rows/block
        __shared__ float hfr[76][8];
        __shared__ float hcnt[76][8];
        __shared__ int   colL[SUPPORT];
        __shared__ int   offL[NCLS + 1];
        __shared__ int   cntL[NCLS], curL[NCLS];
        for (int i = tid; i < 76 * 8; i += 256) {
            (&hfr[0][0])[i] = 0.0f;
            (&hcnt[0][0])[i] = 0.0f;
        }
        if (tid < NCLS) cntL[tid] = 0;
        __syncthreads();
        const int j0 = tid, j1 = tid + 256;
        const int l0 = labels[j0], l1 = labels[j1];
        atomicAdd(&cntL[l0], 1);
        atomicAdd(&cntL[l1], 1);
        __syncthreads();
        if (tid == 0) {
            int o = 0;
            for (int i = 0; i < NCLS; ++i) { offL[i] = o; curL[i] = o; o += cntL[i]; }
            offL[NCLS] = o;
        }
        __syncthreads();
        colL[atomicAdd(&curL[l0], 1)] = j0;
        colL[atomicAdd(&curL[l1], 1)] = j1;
        __syncthreads();

        const int sl = tid & 7;
        const int r0 = blockIdx.x * PH_ROWS + (tid >> 3);   // rows r0 + {0,32,64,96}
        #pragma unroll
        for (int rr = 0; rr < 4; ++rr) {
            const int r    = r0 + rr * 32;
            const int c    = labels[SUPPORT + r];
            const int base = offL[c];
            const int cnt  = offL[c + 1] - base;
            const float* rptr = ip + (size_t)r * SUPPORT;
            for (int j = sl; j < cnt; j += 8) {
                const float s  = rptr[colL[base + j]];
                const float u  = s * 75.0f;
                const float fl = floorf(u);
                const int idx  = (int)fl;            // 0..74 guaranteed (s in [0,1))
                lds_fadd(&hfr[idx][sl],  u - fl);
                lds_fadd(&hcnt[idx][sl], 1.0f);
            }
        }
        __syncthreads();
        if (tid < 76) {
            float a = 0.0f, b = 0.0f;
            #pragma unroll
            for (int r = 0; r < 8; ++r) { a += hfr[tid][r]; b += hcnt[tid][r]; }
            if (a != 0.0f) unsafeAtomicAdd(&ws->hist_fr_sp[blockIdx.x & 7][tid], a);
            if (b != 0.0f) unsafeAtomicAdd(&ws->hist_cnt_sp[blockIdx.x & 7][tid], b);
        }
    } else {
        // ---- direct loss: 4 rows per wave, 16-lane group per row
        __shared__ float red[4];
        const int bid  = blockIdx.x - PH_BLK;
        const int wid  = tid >> 6;
        const int lane = tid & 63;
        const int sub  = lane >> 4;
        const int grpb = lane & ~15;

        float lsum = 0.0f;
        for (int q = bid * 4 + wid; q < NQUAD; q += DR_BLK * 4) {
            const float4 x = reinterpret_cast<const float4*>(logits)[q * 64 + lane];
            const int lab  = labels[SUPPORT + q * 4 + sub];
            float m = fmaxf(fmaxf(x.x, x.y), fmaxf(x.z, x.w));
            #pragma unroll
            for (int off = 1; off < 16; off <<= 1) m = fmaxf(m, __shfl_xor(m, off));
            float e = __expf(x.x - m) + __expf(x.y - m) + __expf(x.z - m) + __expf(x.w - m);
            #pragma unroll
            for (int off = 1; off < 16; off <<= 1) e += __shfl_xor(e, off);
            const int l3 = lab & 3;
            const float sel = l3 == 0 ? x.x : l3 == 1 ? x.y : l3 == 2 ? x.z : x.w;
            const float xl = __shfl(sel, grpb + (lab >> 2));
            if ((lane & 15) == 0) lsum += m + __logf(e) - xl;
        }
        #pragma unroll
        for (int off = 1; off < 64; off <<= 1) lsum += __shfl_xor(lsum, off);
        if (lane == 0) red[wid] = lsum;
        __syncthreads();
        if (tid == 0)
            unsafeAtomicAdd(&ws->nll_sum[bid & 7], red[0] + red[1] + red[2] + red[3]);
    }
}

// ---------------------------------------------------------------- stream (cdf prologue folded in)
// Main loop loads are NONTEMPORAL (no-allocate hint): the 133.5 MB is
// read-once, so dead-line fills were competing with demand fetches.
__global__ __launch_bounds__(256, 4) void stream_kernel(const float* __restrict__ ip,
                                                        Accum* __restrict__ ws) {
    __shared__ float2 tab[76 * 32];   // 32-way replicated fused table (19.5 KB)
    __shared__ float Sfr[80], Cnt[80];
    __shared__ float Atab[80], Btab[80];
    __shared__ float red[4];
    const int tid = threadIdx.x;

    if (tid < 76) {
        float a = 0.0f, b = 0.0f;
        #pragma unroll
        for (int r = 0; r < 8; ++r) { a += ws->hist_fr_sp[r][tid]; b += ws->hist_cnt_sp[r][tid]; }
        Sfr[tid] = a; Cnt[tid] = b;
    }
    if (tid >= 76 && tid < 80) { Sfr[tid] = 0.0f; Cnt[tid] = 0.0f; }
    __syncthreads();
    if (tid == 0) {
        if (blockIdx.x == 0) {
            float prevS = 0.0f, prevN = 0.0f, cacc = 0.0f;
            double sp = 0.0, pn = 0.0;
            for (int i = 0; i <= 76; ++i) {
                const float Si = (i < 76) ? Sfr[i] : 0.0f;
                const float Ni = (i < 76) ? Cnt[i] : 0.0f;
                const float Hi = Si + prevN - prevS;     // pos soft-hist H[i]
                cacc += Hi;                              // C[i]
                if (i >= 1) {
                    const int k = i - 1;
                    Atab[k] = cacc + (float)k * Hi;      // C[k+1] + k*H[k+1]
                    Btab[k] = Hi;                        // H[k+1]
                    sp += (double)prevN * cacc - (double)prevS * Hi;
                }
                pn += (double)Ni;
                prevS = Si; prevN = Ni;
            }
            ws->spos = (float)sp; ws->pos_num = (float)pn;
        } else {
            float prevS = 0.0f, prevN = 0.0f, cacc = 0.0f;
            for (int i = 0; i <= 76; ++i) {
                const float Si = (i < 76) ? Sfr[i] : 0.0f;
                const float Ni = (i < 76) ? Cnt[i] : 0.0f;
                const float Hi = Si + prevN - prevS;
                cacc += Hi;
                if (i >= 1) {
                    const int k = i - 1;
                    Atab[k] = cacc + (float)k * Hi;
                    Btab[k] = Hi;
                }
                prevS = Si; prevN = Ni;
            }
        }
    }
    __syncthreads();
    const int c32 = tid & 31;
    for (int i = tid; i < 76 * 32; i += 256)
        tab[i] = make_float2(Atab[i >> 5], Btab[i >> 5]);
    __syncthreads();

    const f4* base = reinterpret_cast<const f4*>(ip)
                   + (size_t)blockIdx.x * (GS_ROWS * 128) + tid;

    float sa0 = 0.0f, sb0 = 0.0f, sa1 = 0.0f, sb1 = 0.0f;
    f4 qa0, qa1, qa2, qa3, qa4, qa5, qa6, qa7;
    f4 qb0, qb1, qb2, qb3, qb4, qb5, qb6, qb7;

#define NTL(P) __builtin_nontemporal_load(P)
#define LDA(T) { qa0 = NTL(base + ((T)+0)*256); qa1 = NTL(base + ((T)+1)*256); \
                 qa2 = NTL(base + ((T)+2)*256); qa3 = NTL(base + ((T)+3)*256); \
                 qa4 = NTL(base + ((T)+4)*256); qa5 = NTL(base + ((T)+5)*256); \
                 qa6 = NTL(base + ((T)+6)*256); qa7 = NTL(base + ((T)+7)*256); }
#define LDB(T) { qb0 = NTL(base + ((T)+0)*256); qb1 = NTL(base + ((T)+1)*256); \
                 qb2 = NTL(base + ((T)+2)*256); qb3 = NTL(base + ((T)+3)*256); \
                 qb4 = NTL(base + ((T)+4)*256); qb5 = NTL(base + ((T)+5)*256); \
                 qb6 = NTL(base + ((T)+6)*256); qb7 = NTL(base + ((T)+7)*256); }
#define PE(S, SA, SB) { const float u = (S) * 75.0f; const int idx = (int)u;   \
                        const float2 ab = tab[(idx << 5) + c32];               \
                        SA += ab.x; SB = fmaf(u, ab.y, SB); }
#define P1(Q) { PE(Q.x, sa0, sb0) PE(Q.y, sa1, sb1) PE(Q.z, sa0, sb0) PE(Q.w, sa1, sb1) }
#define PA()  { P1(qa0) P1(qa1) P1(qa2) P1(qa3) P1(qa4) P1(qa5) P1(qa6) P1(qa7) }
#define PB()  { P1(qb0) P1(qb1) P1(qb2) P1(qb3) P1(qb4) P1(qb5) P1(qb6) P1(qb7) }

    LDA(0);
    LDB(8);
    PA();  LDA(16);
    PB();  LDB(24);
    PA();
    PB();

#undef NTL
#undef LDA
#undef LDB
#undef PE
#undef P1
#undef PA
#undef PB

    float s_all = (sa0 + sa1) - (sb0 + sb1);
    #pragma unroll
    for (int off = 1; off < 64; off <<= 1) s_all += __shfl_xor(s_all, off);
    if ((tid & 63) == 0) red[tid >> 6] = s_all;
    __syncthreads();
    if (tid == 0)
        unsafeAtomicAdd(&ws->sum_all[blockIdx.x & 7], red[0] + red[1] + red[2] + red[3]);
}

// ---------------------------------------------------------------- finalize
__global__ void final_kernel(const Accum* __restrict__ ws, float* __restrict__ out) {
    if (threadIdx.x == 0 && blockIdx.x == 0) {
        double S = 0.0, nll = 0.0;
        for (int i = 0; i < 8; ++i) {
            S   += (double)ws->sum_all[i];
            nll += (double)ws->nll_sum[i];
        }
        const double pos = (double)ws->pos_num;
        const double tot = (double)TARGET * (double)SUPPORT;
        out[0] = (float)((S - (double)ws->spos) / (pos * (tot - pos)));
        out[1] = (float)(nll / (double)TARGET);
    }
}

// ---------------------------------------------------------------- launch
extern "C" void kernel_launch(void* const* d_in, const int* in_sizes, int n_in,
                              void* d_out, int out_size, void* d_ws, size_t ws_size,
                              hipStream_t stream) {
    const float* logits = (const float*)d_in[0];   // (65024, 64) f32
    const float* ip     = (const float*)d_in[1];   // (65024, 512) f32
    const int*   labels = (const int*)d_in[2];     // (65536,) int
    float* out = (float*)d_out;
    Accum* ws  = (Accum*)d_ws;

    hipMemsetAsync(ws, 0, sizeof(Accum), stream);
    phdir_kernel<<<PH_BLK + DR_BLK, 256, 0, stream>>>(ip, logits, labels, ws);
    stream_kernel<<<GS_BLK, 256, 0, stream>>>(ip, ws);
    final_kernel<<<1, 64, 0, stream>>>(ws, out);
}